// Round 1
// baseline (857.403 us; speedup 1.0000x reference)
//
#include <hip/hip_runtime.h>
#include <stdint.h>

#define NN 100000
#define NE 1600000
#define MAXD 64

using short8 = __attribute__((ext_vector_type(8))) short;
using f32x4  = __attribute__((ext_vector_type(4))) float;
typedef unsigned short ushort_t;

__device__ __forceinline__ ushort_t f2bf(float f){
  union { float f; uint32_t u; } v; v.f = f;
  uint32_t u = v.u;
  uint32_t r = (u + 0x7fffu + ((u >> 16) & 1u)) >> 16;
  return (ushort_t)r;
}
__device__ __forceinline__ float bf2f(ushort_t h){
  union { uint32_t u; float f; } v; v.u = ((uint32_t)h) << 16;
  return v.f;
}

// ---------------- dtype detect: int64 edge_index has all-zero odd words ----
__global__ void k_detect(const unsigned* ei, int* flag){
  __shared__ int any;
  if(threadIdx.x == 0) any = 0;
  __syncthreads();
  unsigned w = ei[2*threadIdx.x + 1];
  if(w) atomicOr(&any, 1);
  __syncthreads();
  if(threadIdx.x == 0) *flag = (any == 0) ? 1 : 0;   // 1 => int64
}

// ---------------- per-node edge list (append) ------------------------------
__global__ void k_build(const int* ei, const int* flag, int* cursor, int* list){
  int e = blockIdx.x * blockDim.x + threadIdx.x;
  if(e >= NE) return;
  bool i64 = (*flag != 0);
  int src, dst;
  if(i64){
    const long long* p = (const long long*)ei;
    src = (int)p[e]; dst = (int)p[NE + e];
  } else {
    src = ei[e]; dst = ei[NE + e];
  }
  if((unsigned)src >= NN || (unsigned)dst >= NN) return;
  int pos = atomicAdd(&cursor[dst], 1);
  if(pos < MAXD) list[dst*MAXD + pos] = src;
}

// ---------------- weight fragment prep -------------------------------------
// Wcat[k][n]: n<128 -> wa[k][n]-wa[C+k][n] ; n>=128 -> wa[C+k][n-128]; k>=C -> 0
// frag layout: dst[((nt*KT+kt)*64 + lane)*8 + j], k = kt*32+(lane>>4)*8+j, n = nt*16+(lane&15)
__global__ void k_wcatfrag(const float* wa, ushort_t* dst, int C, int KT){
  int idx = blockIdx.x*blockDim.x + threadIdx.x;
  int total = 16*KT*64*8;
  if(idx >= total) return;
  int j = idx & 7, lane = (idx>>3)&63;
  int rest = idx >> 9;
  int kt = rest % KT, nt = rest / KT;
  int k = kt*32 + ((lane>>4)<<3) + j;
  int n = nt*16 + (lane & 15);
  float v = 0.f;
  if(k < C) v = (n < 128) ? (wa[k*128+n] - wa[(C+k)*128+n]) : wa[(C+k)*128 + (n-128)];
  dst[idx] = f2bf(v);
}

__global__ void k_wbfrag(const float* wb, ushort_t* dst){
  int idx = blockIdx.x*blockDim.x + threadIdx.x;     // 8*4*64*8 = 16384
  if(idx >= 8*4*64*8) return;
  int j = idx & 7, lane = (idx>>3)&63;
  int kt = (idx>>9)&3, nt = idx>>11;
  int k = kt*32 + ((lane>>4)<<3) + j;
  int n = nt*16 + (lane & 15);
  dst[idx] = f2bf(wb[k*128 + n]);
}

// ---------------- table GEMM: [A | B] = x @ Wcat (+bias on A half) ---------
template<int KT, int ROWLEN, bool SPLIT>
__global__ __launch_bounds__(256)
void k_gemm(const void* xin_, const ushort_t* __restrict__ wfrag,
            const float* __restrict__ bias, float* __restrict__ Atab,
            ushort_t* __restrict__ Btab)
{
  constexpr int K  = KT*32;
  constexpr int RB = K*2 + 16;              // padded LDS row stride, bytes
  __shared__ ushort_t shHi[64*RB/2];
  __shared__ ushort_t shLo[SPLIT ? 64*RB/2 : 2];

  const int t = threadIdx.x;
  const int wave = t >> 6, lane = t & 63;
  const int l15 = lane & 15, lg = lane >> 4;

  short8 bf[4][KT];
  #pragma unroll
  for(int ntl=0; ntl<4; ntl++)
    #pragma unroll
    for(int kt=0; kt<KT; kt++){
      int nt = wave*4 + ntl;
      bf[ntl][kt] = *(const short8*)&wfrag[((nt*KT + kt)*64 + lane)*8];
    }
  float bv[4] = {0.f,0.f,0.f,0.f};
  if(wave < 2){
    #pragma unroll
    for(int ntl=0; ntl<4; ntl++) bv[ntl] = bias[wave*64 + ntl*16 + l15];
  }

  const int row0 = blockIdx.x * 64;

  constexpr int GROUPS = 64*(K/8);
  #pragma unroll
  for(int it=0; it<GROUPS/256; it++){
    int gi  = t + it*256;
    int row = gi / (K/8), kg = gi % (K/8);
    int gr  = row0 + row;
    int off = (row*RB + kg*16) >> 1;
    if constexpr (SPLIT){
      const float* xin = (const float*)xin_;
      short8 hi8, lo8;
      #pragma unroll
      for(int j=0;j<8;j++){
        int k = kg*8 + j;
        float v = (gr < NN && k < ROWLEN) ? xin[(size_t)gr*ROWLEN + k] : 0.f;
        ushort_t h = f2bf(v);
        hi8[j] = (short)h;
        lo8[j] = (short)f2bf(v - bf2f(h));
      }
      *(short8*)&shHi[off] = hi8;
      *(short8*)&shLo[off] = lo8;
    } else {
      const ushort_t* xb = (const ushort_t*)xin_;
      short8 h8 = {0,0,0,0,0,0,0,0};
      if(gr < NN) h8 = *(const short8*)&xb[(size_t)gr*ROWLEN + kg*8];
      *(short8*)&shHi[off] = h8;
    }
  }
  __syncthreads();

  #pragma unroll
  for(int mc=0; mc<4; mc++){
    f32x4 acc[4];
    #pragma unroll
    for(int ntl=0; ntl<4; ntl++) acc[ntl] = (f32x4){0.f,0.f,0.f,0.f};
    #pragma unroll
    for(int kt=0; kt<KT; kt++){
      int off = ((mc*16 + l15)*RB + kt*64 + lg*16) >> 1;
      short8 ah = *(const short8*)&shHi[off];
      #pragma unroll
      for(int ntl=0; ntl<4; ntl++)
        acc[ntl] = __builtin_amdgcn_mfma_f32_16x16x32_bf16(ah, bf[ntl][kt], acc[ntl], 0,0,0);
      if constexpr (SPLIT){
        short8 al = *(const short8*)&shLo[off];
        #pragma unroll
        for(int ntl=0; ntl<4; ntl++)
          acc[ntl] = __builtin_amdgcn_mfma_f32_16x16x32_bf16(al, bf[ntl][kt], acc[ntl], 0,0,0);
      }
    }
    #pragma unroll
    for(int ntl=0; ntl<4; ntl++){
      #pragma unroll
      for(int q=0; q<4; q++){
        int gr = row0 + mc*16 + lg*4 + q;
        if(gr < NN){
          if(wave < 2){
            int ch = wave*64 + ntl*16 + l15;
            Atab[(size_t)gr*128 + ch] = acc[ntl][q] + bv[ntl];
          } else {
            int ch = (wave-2)*64 + ntl*16 + l15;
            Btab[(size_t)gr*128 + ch] = f2bf(acc[ntl][q]);
          }
        }
      }
    }
  }
}

// ---------------- edge kernel: out[n] = relu(max_e relu(A[n]+B[src]) @ wb + bb)
template<bool F32OUT>
__global__ __launch_bounds__(256)
void k_edge(const float* __restrict__ Atab, const ushort_t* __restrict__ Btab,
            const ushort_t* __restrict__ wbfrag, const float* __restrict__ bias2,
            const int* __restrict__ deg, const int* __restrict__ list,
            float* __restrict__ outF, ushort_t* __restrict__ outB)
{
  __shared__ float    shA[128];
  __shared__ ushort_t shH[16*272/2];      // 16 edge rows, 272B padded stride

  const int t = threadIdx.x;
  const int wave = t >> 6, lane = t & 63;
  const int l15 = lane & 15, lg = lane >> 4;
  const int eg  = t >> 4;                 // edge slot 0..15
  const int ch8 = (t & 15) * 8;           // h-phase channel group

  short8 wf[2][4];
  #pragma unroll
  for(int ntl=0; ntl<2; ntl++)
    #pragma unroll
    for(int kt=0; kt<4; kt++){
      int nt = wave*2 + ntl;
      wf[ntl][kt] = *(const short8*)&wbfrag[((nt*4 + kt)*64 + lane)*8];
    }
  float bbv[2];
  #pragma unroll
  for(int ntl=0; ntl<2; ntl++) bbv[ntl] = bias2[wave*32 + ntl*16 + l15];

  for(int n = blockIdx.x; n < NN; n += gridDim.x){
    int d = deg[n]; if(d > MAXD) d = MAXD;
    if(d == 0){
      if(lane < 16){
        #pragma unroll
        for(int ntl=0; ntl<2; ntl++){
          int ch = wave*32 + ntl*16 + lane;
          if(F32OUT) outF[(size_t)n*128 + ch] = 0.f;
          else       outB[(size_t)n*128 + ch] = 0;
        }
      }
      continue;
    }
    __syncthreads();                       // shA/shH free from previous node
    if(t < 128) shA[t] = Atab[(size_t)n*128 + t];
    __syncthreads();

    float m0 = -3.0e38f, m1 = -3.0e38f;
    const int* lst = &list[(size_t)n*MAXD];
    int nch = (d + 15) >> 4;
    for(int c = 0; c < nch; c++){
      int ei = c*16 + eg; if(ei >= d) ei = d - 1;   // pad by replication
      int s = lst[ei];
      short8 bvv = *(const short8*)&Btab[(size_t)s*128 + ch8];
      short8 hw;
      #pragma unroll
      for(int j=0;j<8;j++){
        float h = shA[ch8 + j] + bf2f((ushort_t)bvv[j]);
        h = h > 0.f ? h : 0.f;
        hw[j] = (short)f2bf(h);
      }
      __syncthreads();                     // prev MFMA reads done
      *(short8*)&shH[(eg*272 + (t&15)*16) >> 1] = hw;
      __syncthreads();                     // h tile visible

      f32x4 macc0 = (f32x4){0.f,0.f,0.f,0.f};
      f32x4 macc1 = (f32x4){0.f,0.f,0.f,0.f};
      #pragma unroll
      for(int kt=0; kt<4; kt++){
        short8 a = *(const short8*)&shH[(l15*272 + kt*64 + lg*16) >> 1];
        macc0 = __builtin_amdgcn_mfma_f32_16x16x32_bf16(a, wf[0][kt], macc0, 0,0,0);
        macc1 = __builtin_amdgcn_mfma_f32_16x16x32_bf16(a, wf[1][kt], macc1, 0,0,0);
      }
      float mm0 = fmaxf(fmaxf(macc0[0],macc0[1]), fmaxf(macc0[2],macc0[3]));
      mm0 = fmaxf(mm0, __shfl_xor(mm0, 16, 64));
      mm0 = fmaxf(mm0, __shfl_xor(mm0, 32, 64));
      m0  = fmaxf(m0, mm0);
      float mm1 = fmaxf(fmaxf(macc1[0],macc1[1]), fmaxf(macc1[2],macc1[3]));
      mm1 = fmaxf(mm1, __shfl_xor(mm1, 16, 64));
      mm1 = fmaxf(mm1, __shfl_xor(mm1, 32, 64));
      m1  = fmaxf(m1, mm1);
    }
    if(lane < 16){
      float v0 = fmaxf(m0 + bbv[0], 0.f);
      float v1 = fmaxf(m1 + bbv[1], 0.f);
      int ch = wave*32 + lane;
      if(F32OUT){
        outF[(size_t)n*128 + ch]      = v0;
        outF[(size_t)n*128 + ch + 16] = v1;
      } else {
        outB[(size_t)n*128 + ch]      = f2bf(v0);
        outB[(size_t)n*128 + ch + 16] = f2bf(v1);
      }
    }
  }
}

// ---------------- final: concat -> maxpool(24) -> dot(fw)+fb ---------------
template<bool F32IN>
__global__ __launch_bounds__(256)
void k_final(const void* x2_, const void* x4_, const void* x6_,
             const float* __restrict__ fw, const float* __restrict__ fb,
             float* __restrict__ out)
{
  __shared__ float arr[4][384];
  int wave = threadIdx.x >> 6, lane = threadIdx.x & 63;
  int n = blockIdx.x*4 + wave;
  if(n < NN){
    const void* xs[3] = {x2_, x4_, x6_};
    #pragma unroll
    for(int tt=0; tt<3; tt++){
      float a, b;
      if(F32IN){
        const float* p = (const float*)xs[tt] + (size_t)n*128 + lane*2;
        a = p[0]; b = p[1];
      } else {
        const ushort_t* p = (const ushort_t*)xs[tt] + (size_t)n*128 + lane*2;
        a = bf2f(p[0]); b = bf2f(p[1]);
      }
      arr[wave][tt*128 + lane*2]     = a;
      arr[wave][tt*128 + lane*2 + 1] = b;
    }
  }
  __syncthreads();
  if(n < NN && lane < 16){
    float m = -3.0e38f;
    #pragma unroll
    for(int j=0;j<24;j++) m = fmaxf(m, arr[wave][lane*24 + j]);
    float p = m * fw[lane];
    #pragma unroll
    for(int off=1; off<16; off<<=1) p += __shfl_xor(p, off, 64);
    if(lane == 0) out[n] = p + fb[0];
  }
}

// ---------------- host ------------------------------------------------------
extern "C" void kernel_launch(void* const* d_in, const int* in_sizes, int n_in,
                              void* d_out, int out_size, void* d_ws, size_t ws_size,
                              hipStream_t stream)
{
  const float* x   = (const float*)d_in[0];
  const void*  ei  = d_in[1];
  const float* w1a = (const float*)d_in[2];
  const float* b1a = (const float*)d_in[3];
  const float* w1b = (const float*)d_in[4];
  const float* b1b = (const float*)d_in[5];
  const float* w2a = (const float*)d_in[6];
  const float* b2a = (const float*)d_in[7];
  const float* w2b = (const float*)d_in[8];
  const float* b2b = (const float*)d_in[9];
  const float* w3a = (const float*)d_in[10];
  const float* b3a = (const float*)d_in[11];
  const float* w3b = (const float*)d_in[12];
  const float* b3b = (const float*)d_in[13];
  const float* fw  = (const float*)d_in[14];
  const float* fb  = (const float*)d_in[15];

  char* ws = (char*)d_ws;
  size_t off = 0;
  auto alloc = [&](size_t bytes) -> void* {
    void* p = ws + off;
    off = (off + bytes + 255) & ~(size_t)255;
    return p;
  };
  int*      flag   = (int*)alloc(4);
  int*      cursor = (int*)alloc((size_t)NN*4);
  int*      list   = (int*)alloc((size_t)NN*MAXD*4);
  float*    Atab   = (float*)alloc((size_t)NN*128*4);
  ushort_t* Btab   = (ushort_t*)alloc((size_t)NN*128*2);
  ushort_t* wf1    = (ushort_t*)alloc(16*1*64*8*2);
  ushort_t* wf2    = (ushort_t*)alloc(16*4*64*8*2);
  ushort_t* wf3    = (ushort_t*)alloc(16*4*64*8*2);
  ushort_t* wbf1   = (ushort_t*)alloc(8*4*64*8*2);
  ushort_t* wbf2   = (ushort_t*)alloc(8*4*64*8*2);
  ushort_t* wbf3   = (ushort_t*)alloc(8*4*64*8*2);

  size_t fixed = off;
  bool planA = (ws_size >= fixed + 3*(size_t)NN*128*4 + 1024);
  void *x2, *x4, *x6;
  size_t xbytes = planA ? (size_t)NN*128*4 : (size_t)NN*128*2;
  x2 = alloc(xbytes); x4 = alloc(xbytes); x6 = alloc(xbytes);

  hipMemsetAsync(cursor, 0, (size_t)NN*4, stream);
  k_detect<<<1, 128, 0, stream>>>((const unsigned*)ei, flag);
  k_build<<<(NE + 255)/256, 256, 0, stream>>>((const int*)ei, flag, cursor, list);

  k_wcatfrag<<<(16*1*64*8 + 255)/256, 256, 0, stream>>>(w1a, wf1, 24, 1);
  k_wcatfrag<<<(16*4*64*8 + 255)/256, 256, 0, stream>>>(w2a, wf2, 128, 4);
  k_wcatfrag<<<(16*4*64*8 + 255)/256, 256, 0, stream>>>(w3a, wf3, 128, 4);
  k_wbfrag<<<64, 256, 0, stream>>>(w1b, wbf1);
  k_wbfrag<<<64, 256, 0, stream>>>(w2b, wbf2);
  k_wbfrag<<<64, 256, 0, stream>>>(w3b, wbf3);

  const int GT = (NN + 63)/64;
  const int EG = 4096;

  k_gemm<1,24,true><<<GT, 256, 0, stream>>>(x, wf1, b1a, Atab, Btab);
  if(planA){
    k_edge<true><<<EG, 256, 0, stream>>>(Atab, Btab, wbf1, b1b, cursor, list, (float*)x2, nullptr);
    k_gemm<4,128,true><<<GT, 256, 0, stream>>>(x2, wf2, b2a, Atab, Btab);
    k_edge<true><<<EG, 256, 0, stream>>>(Atab, Btab, wbf2, b2b, cursor, list, (float*)x4, nullptr);
    k_gemm<4,128,true><<<GT, 256, 0, stream>>>(x4, wf3, b3a, Atab, Btab);
    k_edge<true><<<EG, 256, 0, stream>>>(Atab, Btab, wbf3, b3b, cursor, list, (float*)x6, nullptr);
    k_final<true><<<(NN + 3)/4, 256, 0, stream>>>(x2, x4, x6, fw, fb, (float*)d_out);
  } else {
    k_edge<false><<<EG, 256, 0, stream>>>(Atab, Btab, wbf1, b1b, cursor, list, nullptr, (ushort_t*)x2);
    k_gemm<4,128,false><<<GT, 256, 0, stream>>>(x2, wf2, b2a, Atab, Btab);
    k_edge<false><<<EG, 256, 0, stream>>>(Atab, Btab, wbf2, b2b, cursor, list, nullptr, (ushort_t*)x4);
    k_gemm<4,128,false><<<GT, 256, 0, stream>>>(x4, wf3, b3a, Atab, Btab);
    k_edge<false><<<EG, 256, 0, stream>>>(Atab, Btab, wbf3, b3b, cursor, list, nullptr, (ushort_t*)x6);
    k_final<false><<<(NN + 3)/4, 256, 0, stream>>>(x2, x4, x6, fw, fb, (float*)d_out);
  }
}

// Round 3
// 841.976 us; speedup vs baseline: 1.0183x; 1.0183x over previous
//
#include <hip/hip_runtime.h>
#include <stdint.h>

#define NN 100000
#define NE 1600000
#define MAXD 64

using short8 = __attribute__((ext_vector_type(8))) short;
using f32x4  = __attribute__((ext_vector_type(4))) float;
using u32x4  = __attribute__((ext_vector_type(4))) unsigned int;
typedef unsigned short ushort_t;

__device__ __forceinline__ ushort_t f2bf(float f){
  union { float f; uint32_t u; } v; v.f = f;
  uint32_t u = v.u;
  uint32_t r = (u + 0x7fffu + ((u >> 16) & 1u)) >> 16;
  return (ushort_t)r;
}
__device__ __forceinline__ float bf2f(ushort_t h){
  union { uint32_t u; float f; } v; v.u = ((uint32_t)h) << 16;
  return v.f;
}

// ---------------- dtype detect: int64 edge_index has all-zero odd words ----
__global__ void k_detect(const unsigned* ei, int* flag){
  __shared__ int any;
  if(threadIdx.x == 0) any = 0;
  __syncthreads();
  unsigned w = ei[2*threadIdx.x + 1];
  if(w) atomicOr(&any, 1);
  __syncthreads();
  if(threadIdx.x == 0) *flag = (any == 0) ? 1 : 0;   // 1 => int64
}

// ---------------- per-node edge list (append) ------------------------------
__global__ void k_build(const int* ei, const int* flag, int* cursor, int* list){
  int e = blockIdx.x * blockDim.x + threadIdx.x;
  if(e >= NE) return;
  bool i64 = (*flag != 0);
  int src, dst;
  if(i64){
    const long long* p = (const long long*)ei;
    src = (int)p[e]; dst = (int)p[NE + e];
  } else {
    src = ei[e]; dst = ei[NE + e];
  }
  if((unsigned)src >= NN || (unsigned)dst >= NN) return;
  int pos = atomicAdd(&cursor[dst], 1);
  if(pos < MAXD) list[dst*MAXD + pos] = src;
}

// ---------------- weight fragment prep -------------------------------------
__global__ void k_wcatfrag(const float* wa, ushort_t* dst, int C, int KT){
  int idx = blockIdx.x*blockDim.x + threadIdx.x;
  int total = 16*KT*64*8;
  if(idx >= total) return;
  int j = idx & 7, lane = (idx>>3)&63;
  int rest = idx >> 9;
  int kt = rest % KT, nt = rest / KT;
  int k = kt*32 + ((lane>>4)<<3) + j;
  int n = nt*16 + (lane & 15);
  float v = 0.f;
  if(k < C) v = (n < 128) ? (wa[k*128+n] - wa[(C+k)*128+n]) : wa[(C+k)*128 + (n-128)];
  dst[idx] = f2bf(v);
}

__global__ void k_wbfrag(const float* wb, ushort_t* dst){
  int idx = blockIdx.x*blockDim.x + threadIdx.x;     // 8*4*64*8 = 16384
  if(idx >= 8*4*64*8) return;
  int j = idx & 7, lane = (idx>>3)&63;
  int kt = (idx>>9)&3, nt = idx>>11;
  int k = kt*32 + ((lane>>4)<<3) + j;
  int n = nt*16 + (lane & 15);
  dst[idx] = f2bf(wb[k*128 + n]);
}

// ---------------- table GEMM: [A | B] = x @ Wcat (+bias on A half) ---------
template<int KT, int ROWLEN, bool SPLIT>
__global__ __launch_bounds__(256)
void k_gemm(const void* xin_, const ushort_t* __restrict__ wfrag,
            const float* __restrict__ bias, float* __restrict__ Atab,
            ushort_t* __restrict__ Btab)
{
  constexpr int K  = KT*32;
  constexpr int RB = K*2 + 16;              // padded LDS row stride, bytes
  __shared__ ushort_t shHi[64*RB/2];
  __shared__ ushort_t shLo[SPLIT ? 64*RB/2 : 2];

  const int t = threadIdx.x;
  const int wave = t >> 6, lane = t & 63;
  const int l15 = lane & 15, lg = lane >> 4;

  short8 bf[4][KT];
  #pragma unroll
  for(int ntl=0; ntl<4; ntl++)
    #pragma unroll
    for(int kt=0; kt<KT; kt++){
      int nt = wave*4 + ntl;
      bf[ntl][kt] = *(const short8*)&wfrag[((nt*KT + kt)*64 + lane)*8];
    }
  float bv[4] = {0.f,0.f,0.f,0.f};
  if(wave < 2){
    #pragma unroll
    for(int ntl=0; ntl<4; ntl++) bv[ntl] = bias[wave*64 + ntl*16 + l15];
  }

  const int row0 = blockIdx.x * 64;

  constexpr int GROUPS = 64*(K/8);
  #pragma unroll
  for(int it=0; it<GROUPS/256; it++){
    int gi  = t + it*256;
    int row = gi / (K/8), kg = gi % (K/8);
    int gr  = row0 + row;
    int off = (row*RB + kg*16) >> 1;
    if constexpr (SPLIT){
      const float* xin = (const float*)xin_;
      short8 hi8, lo8;
      #pragma unroll
      for(int j=0;j<8;j++){
        int k = kg*8 + j;
        float v = (gr < NN && k < ROWLEN) ? xin[(size_t)gr*ROWLEN + k] : 0.f;
        ushort_t h = f2bf(v);
        hi8[j] = (short)h;
        lo8[j] = (short)f2bf(v - bf2f(h));
      }
      *(short8*)&shHi[off] = hi8;
      *(short8*)&shLo[off] = lo8;
    } else {
      const ushort_t* xb = (const ushort_t*)xin_;
      short8 h8 = {0,0,0,0,0,0,0,0};
      if(gr < NN) h8 = *(const short8*)&xb[(size_t)gr*ROWLEN + kg*8];
      *(short8*)&shHi[off] = h8;
    }
  }
  __syncthreads();

  #pragma unroll
  for(int mc=0; mc<4; mc++){
    f32x4 acc[4];
    #pragma unroll
    for(int ntl=0; ntl<4; ntl++) acc[ntl] = (f32x4){0.f,0.f,0.f,0.f};
    #pragma unroll
    for(int kt=0; kt<KT; kt++){
      int off = ((mc*16 + l15)*RB + kt*64 + lg*16) >> 1;
      short8 ah = *(const short8*)&shHi[off];
      #pragma unroll
      for(int ntl=0; ntl<4; ntl++)
        acc[ntl] = __builtin_amdgcn_mfma_f32_16x16x32_bf16(ah, bf[ntl][kt], acc[ntl], 0,0,0);
      if constexpr (SPLIT){
        short8 al = *(const short8*)&shLo[off];
        #pragma unroll
        for(int ntl=0; ntl<4; ntl++)
          acc[ntl] = __builtin_amdgcn_mfma_f32_16x16x32_bf16(al, bf[ntl][kt], acc[ntl], 0,0,0);
      }
    }
    #pragma unroll
    for(int ntl=0; ntl<4; ntl++){
      #pragma unroll
      for(int q=0; q<4; q++){
        int gr = row0 + mc*16 + lg*4 + q;
        if(gr < NN){
          if(wave < 2){
            int ch = wave*64 + ntl*16 + l15;
            Atab[(size_t)gr*128 + ch] = acc[ntl][q] + bv[ntl];
          } else {
            int ch = (wave-2)*64 + ntl*16 + l15;
            Btab[(size_t)gr*128 + ch] = f2bf(acc[ntl][q]);
          }
        }
      }
    }
  }
}

// ---------------- edge kernel: out[n] = relu(max_e relu(A[n]+B[src]) @ wb + bb)
// A read direct from global (L1-broadcast), double-buffered h-tile,
// ONE barrier per chunk, B prefetch across chunks, deferred max-reduce.
template<bool F32OUT>
__global__ __launch_bounds__(256)
void k_edge(const float* __restrict__ Atab, const ushort_t* __restrict__ Btab,
            const ushort_t* __restrict__ wbfrag, const float* __restrict__ bias2,
            const int* __restrict__ deg, const int* __restrict__ list,
            float* __restrict__ outF, ushort_t* __restrict__ outB)
{
  __shared__ ushort_t shH[2][16*272/2];   // 2 x (16 edge rows, 272B padded stride)

  const int t = threadIdx.x;
  const int wave = t >> 6, lane = t & 63;
  const int l15 = lane & 15, lg = lane >> 4;
  const int eg  = t >> 4;                 // edge slot 0..15
  const int cg  = t & 15;                 // channel group 0..15 (8 ch each)

  short8 wf[2][4];
  #pragma unroll
  for(int ntl=0; ntl<2; ntl++)
    #pragma unroll
    for(int kt=0; kt<4; kt++){
      int nt = wave*2 + ntl;
      wf[ntl][kt] = *(const short8*)&wbfrag[((nt*4 + kt)*64 + lane)*8];
    }
  float bbv[2];
  #pragma unroll
  for(int ntl=0; ntl<2; ntl++) bbv[ntl] = bias2[wave*32 + ntl*16 + l15];

  int buf = 0;
  for(int n = blockIdx.x; n < NN; n += gridDim.x){
    int d = deg[n]; if(d > MAXD) d = MAXD;
    if(d == 0){
      if(lane < 16){
        #pragma unroll
        for(int ntl=0; ntl<2; ntl++){
          int ch = wave*32 + ntl*16 + lane;
          if(F32OUT) outF[(size_t)n*128 + ch] = 0.f;
          else       outB[(size_t)n*128 + ch] = 0;
        }
      }
      continue;
    }
    const int* lst = &list[(size_t)n*MAXD];
    // this thread's 8 A channels (bias already folded in by k_gemm)
    const float4* ap = (const float4*)&Atab[(size_t)n*128 + cg*8];
    float4 a0 = ap[0], a1 = ap[1];
    float af[8] = {a0.x,a0.y,a0.z,a0.w,a1.x,a1.y,a1.z,a1.w};

    f32x4 mac0 = (f32x4){-3.0e38f,-3.0e38f,-3.0e38f,-3.0e38f};
    f32x4 mac1 = mac0;

    int nch = (d + 15) >> 4;
    // prefetch chunk 0's B row slice
    int ei0 = (eg < d) ? eg : d - 1;
    short8 b8 = *(const short8*)&Btab[(size_t)lst[ei0]*128 + cg*8];

    for(int c = 0; c < nch; c++){
      // ---- h compute from prefetched b8 ----
      union { short8 s; uint32_t u[4]; } bb; bb.s = b8;
      u32x4 pkv;
      #pragma unroll
      for(int p=0; p<4; p++){
        uint32_t w = bb.u[p];
        float flo = __uint_as_float(w << 16);
        float fhi = __uint_as_float(w & 0xffff0000u);
        float hlo = fmaxf(af[2*p]   + flo, 0.f);
        float hhi = fmaxf(af[2*p+1] + fhi, 0.f);
        uint32_t pw;
        asm("v_cvt_pk_bf16_f32 %0, %1, %2" : "=v"(pw) : "v"(hlo), "v"(hhi));
        pkv[p] = pw;
      }
      *(u32x4*)&shH[buf][(eg*272 + cg*16) >> 1] = pkv;

      // ---- prefetch next chunk's B before the barrier ----
      if(c + 1 < nch){
        int e2 = (c+1)*16 + eg; if(e2 >= d) e2 = d - 1;
        b8 = *(const short8*)&Btab[(size_t)lst[e2]*128 + cg*8];
      }

      __syncthreads();                     // h tile visible; prev-buf reads retired

      f32x4 acc0 = (f32x4){0.f,0.f,0.f,0.f};
      f32x4 acc1 = (f32x4){0.f,0.f,0.f,0.f};
      #pragma unroll
      for(int kt=0; kt<4; kt++){
        short8 a = *(const short8*)&shH[buf][(l15*272 + kt*64 + lg*16) >> 1];
        acc0 = __builtin_amdgcn_mfma_f32_16x16x32_bf16(a, wf[0][kt], acc0, 0,0,0);
        acc1 = __builtin_amdgcn_mfma_f32_16x16x32_bf16(a, wf[1][kt], acc1, 0,0,0);
      }
      #pragma unroll
      for(int q=0; q<4; q++){
        mac0[q] = fmaxf(mac0[q], acc0[q]);
        mac1[q] = fmaxf(mac1[q], acc1[q]);
      }
      buf ^= 1;
    }

    float mm0 = fmaxf(fmaxf(mac0[0],mac0[1]), fmaxf(mac0[2],mac0[3]));
    mm0 = fmaxf(mm0, __shfl_xor(mm0, 16, 64));
    mm0 = fmaxf(mm0, __shfl_xor(mm0, 32, 64));
    float mm1 = fmaxf(fmaxf(mac1[0],mac1[1]), fmaxf(mac1[2],mac1[3]));
    mm1 = fmaxf(mm1, __shfl_xor(mm1, 16, 64));
    mm1 = fmaxf(mm1, __shfl_xor(mm1, 32, 64));

    if(lane < 16){
      float v0 = fmaxf(mm0 + bbv[0], 0.f);
      float v1 = fmaxf(mm1 + bbv[1], 0.f);
      int ch = wave*32 + lane;
      if(F32OUT){
        outF[(size_t)n*128 + ch]      = v0;
        outF[(size_t)n*128 + ch + 16] = v1;
      } else {
        outB[(size_t)n*128 + ch]      = f2bf(v0);
        outB[(size_t)n*128 + ch + 16] = f2bf(v1);
      }
    }
  }
}

// ---------------- final: concat -> maxpool(24) -> dot(fw)+fb ---------------
template<bool F32IN>
__global__ __launch_bounds__(256)
void k_final(const void* x2_, const void* x4_, const void* x6_,
             const float* __restrict__ fw, const float* __restrict__ fb,
             float* __restrict__ out)
{
  __shared__ float arr[4][384];
  int wave = threadIdx.x >> 6, lane = threadIdx.x & 63;
  int n = blockIdx.x*4 + wave;
  if(n < NN){
    const void* xs[3] = {x2_, x4_, x6_};
    #pragma unroll
    for(int tt=0; tt<3; tt++){
      float a, b;
      if(F32IN){
        const float* p = (const float*)xs[tt] + (size_t)n*128 + lane*2;
        a = p[0]; b = p[1];
      } else {
        const ushort_t* p = (const ushort_t*)xs[tt] + (size_t)n*128 + lane*2;
        a = bf2f(p[0]); b = bf2f(p[1]);
      }
      arr[wave][tt*128 + lane*2]     = a;
      arr[wave][tt*128 + lane*2 + 1] = b;
    }
  }
  __syncthreads();
  if(n < NN && lane < 16){
    float m = -3.0e38f;
    #pragma unroll
    for(int j=0;j<24;j++) m = fmaxf(m, arr[wave][lane*24 + j]);
    float p = m * fw[lane];
    #pragma unroll
    for(int off=1; off<16; off<<=1) p += __shfl_xor(p, off, 64);
    if(lane == 0) out[n] = p + fb[0];
  }
}

// ---------------- host ------------------------------------------------------
extern "C" void kernel_launch(void* const* d_in, const int* in_sizes, int n_in,
                              void* d_out, int out_size, void* d_ws, size_t ws_size,
                              hipStream_t stream)
{
  const float* x   = (const float*)d_in[0];
  const void*  ei  = d_in[1];
  const float* w1a = (const float*)d_in[2];
  const float* b1a = (const float*)d_in[3];
  const float* w1b = (const float*)d_in[4];
  const float* b1b = (const float*)d_in[5];
  const float* w2a = (const float*)d_in[6];
  const float* b2a = (const float*)d_in[7];
  const float* w2b = (const float*)d_in[8];
  const float* b2b = (const float*)d_in[9];
  const float* w3a = (const float*)d_in[10];
  const float* b3a = (const float*)d_in[11];
  const float* w3b = (const float*)d_in[12];
  const float* b3b = (const float*)d_in[13];
  const float* fw  = (const float*)d_in[14];
  const float* fb  = (const float*)d_in[15];

  char* ws = (char*)d_ws;
  size_t off = 0;
  auto alloc = [&](size_t bytes) -> void* {
    void* p = ws + off;
    off = (off + bytes + 255) & ~(size_t)255;
    return p;
  };
  int*      flag   = (int*)alloc(4);
  int*      cursor = (int*)alloc((size_t)NN*4);
  int*      list   = (int*)alloc((size_t)NN*MAXD*4);
  float*    Atab   = (float*)alloc((size_t)NN*128*4);
  ushort_t* Btab   = (ushort_t*)alloc((size_t)NN*128*2);
  ushort_t* wf1    = (ushort_t*)alloc(16*1*64*8*2);
  ushort_t* wf2    = (ushort_t*)alloc(16*4*64*8*2);
  ushort_t* wf3    = (ushort_t*)alloc(16*4*64*8*2);
  ushort_t* wbf1   = (ushort_t*)alloc(8*4*64*8*2);
  ushort_t* wbf2   = (ushort_t*)alloc(8*4*64*8*2);
  ushort_t* wbf3   = (ushort_t*)alloc(8*4*64*8*2);

  size_t fixed = off;
  bool planA = (ws_size >= fixed + 3*(size_t)NN*128*4 + 1024);
  void *x2, *x4, *x6;
  size_t xbytes = planA ? (size_t)NN*128*4 : (size_t)NN*128*2;
  x2 = alloc(xbytes); x4 = alloc(xbytes); x6 = alloc(xbytes);

  hipMemsetAsync(cursor, 0, (size_t)NN*4, stream);
  k_detect<<<1, 128, 0, stream>>>((const unsigned*)ei, flag);
  k_build<<<(NE + 255)/256, 256, 0, stream>>>((const int*)ei, flag, cursor, list);

  k_wcatfrag<<<(16*1*64*8 + 255)/256, 256, 0, stream>>>(w1a, wf1, 24, 1);
  k_wcatfrag<<<(16*4*64*8 + 255)/256, 256, 0, stream>>>(w2a, wf2, 128, 4);
  k_wcatfrag<<<(16*4*64*8 + 255)/256, 256, 0, stream>>>(w3a, wf3, 128, 4);
  k_wbfrag<<<64, 256, 0, stream>>>(w1b, wbf1);
  k_wbfrag<<<64, 256, 0, stream>>>(w2b, wbf2);
  k_wbfrag<<<64, 256, 0, stream>>>(w3b, wbf3);

  const int GT = (NN + 63)/64;
  const int EG = 4096;

  k_gemm<1,24,true><<<GT, 256, 0, stream>>>(x, wf1, b1a, Atab, Btab);
  if(planA){
    k_edge<true><<<EG, 256, 0, stream>>>(Atab, Btab, wbf1, b1b, cursor, list, (float*)x2, nullptr);
    k_gemm<4,128,true><<<GT, 256, 0, stream>>>(x2, wf2, b2a, Atab, Btab);
    k_edge<true><<<EG, 256, 0, stream>>>(Atab, Btab, wbf2, b2b, cursor, list, (float*)x4, nullptr);
    k_gemm<4,128,true><<<GT, 256, 0, stream>>>(x4, wf3, b3a, Atab, Btab);
    k_edge<true><<<EG, 256, 0, stream>>>(Atab, Btab, wbf3, b3b, cursor, list, (float*)x6, nullptr);
    k_final<true><<<(NN + 3)/4, 256, 0, stream>>>(x2, x4, x6, fw, fb, (float*)d_out);
  } else {
    k_edge<false><<<EG, 256, 0, stream>>>(Atab, Btab, wbf1, b1b, cursor, list, nullptr, (ushort_t*)x2);
    k_gemm<4,128,false><<<GT, 256, 0, stream>>>(x2, wf2, b2a, Atab, Btab);
    k_edge<false><<<EG, 256, 0, stream>>>(Atab, Btab, wbf2, b2b, cursor, list, nullptr, (ushort_t*)x4);
    k_gemm<4,128,false><<<GT, 256, 0, stream>>>(x4, wf3, b3a, Atab, Btab);
    k_edge<false><<<EG, 256, 0, stream>>>(Atab, Btab, wbf3, b3b, cursor, list, nullptr, (ushort_t*)x6);
    k_final<false><<<(NN + 3)/4, 256, 0, stream>>>(x2, x4, x6, fw, fb, (float*)d_out);
  }
}